// Round 4
// baseline (143.209 us; speedup 1.0000x reference)
//
#include <hip/hip_runtime.h>
#include <hip/hip_fp16.h>

#define NB 4
#define NT 16
#define NN 2048
#define NM 64
#define NK 32
#define NC 1024

// ROCm 7.2 hip_fp16.h has no __hmax2 — emit v_pk_max_f16 directly.
static __device__ inline __half2 h2max(__half2 a, __half2 b) {
    unsigned int ai = *(unsigned int*)&a, bi = *(unsigned int*)&b, di;
    asm("v_pk_max_f16 %0, %1, %2" : "=v"(di) : "v"(ai), "v"(bi));
    return *(__half2*)&di;
}
static __device__ inline unsigned long long u64max(unsigned long long a, unsigned long long b) {
    return a > b ? a : b;
}

// ---------------------------------------------------------------------------
// Kernel A: FPS, one 256-thr block (4 waves) per frame. Thread tid owns the
// CONTIGUOUS index run [tid*8, tid*8+8) so lane order == index order: the
// wave argmax is a 6-step f32 max butterfly + ballot + one shuffle (short
// chain), exact first-index tie-break preserved. Cross-wave combine via u64
// (d2bits<<32 | 2047-idx) in parity-double-buffered LDS: ONE barrier/round.
// Arithmetic (_rn, no FMA) identical to the R2/R3 bit-exact versions.
// ---------------------------------------------------------------------------
__global__ __launch_bounds__(256) void fps_kernel(const float* __restrict__ xyzs,
                                                  float* __restrict__ out_xyz) {
    const int bt = blockIdx.x;
    const float* pts = xyzs + (size_t)bt * NN * 3;
    __shared__ float sX[NN], sY[NN], sZ[NN];
    __shared__ unsigned long long sPart[2][4];
    __shared__ float sAnchor[NM * 3];
    const int tid = threadIdx.x;
    const int lane = tid & 63, wave = tid >> 6;
    float px[8], py[8], pz[8], d2[8];
    #pragma unroll
    for (int j = 0; j < 8; ++j) {
        const int p = tid * 8 + j;            // contiguous per thread
        px[j] = pts[p * 3 + 0];
        py[j] = pts[p * 3 + 1];
        pz[j] = pts[p * 3 + 2];
        sX[p] = px[j]; sY[p] = py[j]; sZ[p] = pz[j];
        d2[j] = 1e10f;
    }
    __syncthreads();
    int last = 0;
    for (int it = 0; it < NM; ++it) {
        const float lx = sX[last], ly = sY[last], lz = sZ[last];
        if (tid == 0) {
            sAnchor[it * 3 + 0] = lx; sAnchor[it * 3 + 1] = ly; sAnchor[it * 3 + 2] = lz;
        }
        float bv = -1.0f; int bp = 0;
        #pragma unroll
        for (int j = 0; j < 8; ++j) {
            const float dx = __fsub_rn(px[j], lx), dy = __fsub_rn(py[j], ly), dz = __fsub_rn(pz[j], lz);
            const float d = __fadd_rn(__fadd_rn(__fmul_rn(dx, dx), __fmul_rn(dy, dy)), __fmul_rn(dz, dz));
            d2[j] = fminf(d2[j], d);
            if (d2[j] > bv) { bv = d2[j]; bp = tid * 8 + j; }  // strict > -> first j wins
        }
        // wave max of VALUE only (6 shfl+max), then resolve min-index by ballot:
        float v = bv;
        #pragma unroll
        for (int off = 32; off > 0; off >>= 1)
            v = fmaxf(v, __shfl_xor(v, off, 64));
        const unsigned long long tied = __ballot(bv == v);
        const int srcLane = (int)(__ffsll((long long)tied) - 1);   // lowest lane = lowest idx
        const int idxw = __shfl(bp, srcLane, 64);
        if (lane == 0)
            sPart[it & 1][wave] = ((unsigned long long)__float_as_uint(v) << 32)
                                | (unsigned)(NN - 1 - idxw);
        __syncthreads();
        const unsigned long long key =
            u64max(u64max(sPart[it & 1][0], sPart[it & 1][1]),
                   u64max(sPart[it & 1][2], sPart[it & 1][3]));
        last = NN - 1 - (int)(key & 0xffffffffull);
    }
    __syncthreads();
    for (int i = tid; i < NM * 3; i += 256)
        out_xyz[bt * NM * 3 + i] = sAnchor[i];
}

// ---------------------------------------------------------------------------
// Kernel B: ball query only. One wave per (bt,m,tap) query -> 48 packed half2
// displacement words into d_ws. 3072 blocks x 256 thr: latency chains hidden
// by 12 short waves/SIMD. No barriers (per-wave-private LDS scratch).
// Semantics identical to the verified R3 ballot-scan (incl. padding rules).
// ---------------------------------------------------------------------------
__global__ __launch_bounds__(256) void bq_kernel(const float* __restrict__ xyzs,
                                                 const float* __restrict__ anchors,
                                                 unsigned int* __restrict__ disp) {
    const int tid = threadIdx.x;
    const int lane = tid & 63, w = tid >> 6;
    const int q = blockIdx.x * 4 + w;      // (bt*NM + m)*3 + tap
    const int bt = q / (NM * 3);
    const int r = q - bt * (NM * 3);
    const int m = r / 3, tap = r - m * 3;
    const int b = bt >> 4, t = bt & 15;
    __shared__ float sD[4][3][NK];
    const float ax = anchors[(bt * NM + m) * 3 + 0];
    const float ay = anchors[(bt * NM + m) * 3 + 1];
    const float az = anchors[(bt * NM + m) * 3 + 2];
    int tsrc = t + tap - 1;
    tsrc = tsrc < 0 ? 0 : (tsrc > NT - 1 ? NT - 1 : tsrc);
    const float* npts = xyzs + ((size_t)(b * NT + tsrc)) * NN * 3;
    int cnt = 0;
    for (int rr = 0; rr < NN / 64 && cnt < NK; ++rr) {
        const int n = rr * 64 + lane;
        const float dx = __fsub_rn(npts[n * 3 + 0], ax);
        const float dy = __fsub_rn(npts[n * 3 + 1], ay);
        const float dz = __fsub_rn(npts[n * 3 + 2], az);
        const float d2v = __fadd_rn(__fadd_rn(__fmul_rn(dx, dx), __fmul_rn(dy, dy)), __fmul_rn(dz, dz));
        const bool valid = d2v < 0.49f;    // f32(0.7*0.7)
        const unsigned long long mask = __ballot(valid);
        const int pos = cnt + (int)__popcll(mask & ((1ull << lane) - 1ull));
        if (valid && pos < NK) {
            sD[w][0][pos] = dx; sD[w][1][pos] = dy; sD[w][2][pos] = dz;
        }
        cnt += (int)__popcll(mask);
    }
    if (cnt < NK) {   // pad with first valid disp (or neigh[0]-anchor if none)
        float fx, fy, fz;
        if (cnt > 0) {
            fx = sD[w][0][0]; fy = sD[w][1][0]; fz = sD[w][2][0];
        } else {
            fx = __fsub_rn(npts[0], ax); fy = __fsub_rn(npts[1], ay); fz = __fsub_rn(npts[2], az);
        }
        if (lane >= cnt && lane < NK) {
            sD[w][0][lane] = fx; sD[w][1][lane] = fy; sD[w][2][lane] = fz;
        }
    }
    // repack f32 -> half2 pairs along k; layout [x:16][y:16][z:16] u32 words
    if (lane < 48) {
        const int c = lane >> 4, j = lane & 15;
        const __half2 hv = __float22half2_rn(make_float2(sD[w][c][2 * j], sD[w][c][2 * j + 1]));
        disp[(size_t)q * 48 + lane] = *(const unsigned int*)&hv;
    }
}

// ---------------------------------------------------------------------------
// Kernel C: conv + k-maxpool + tap-sum. Pure streaming compute: no LDS, no
// barriers. 2048 blocks x 256 thr (32 waves/CU). Block = (bt, m-16-range,
// 128-channel slice); wave = 4 m; lane = 2 channels. Weights converted ONCE
// into registers. Disp: 12 independent b128 L2-hit loads per (m,tap).
// ---------------------------------------------------------------------------
__global__ __launch_bounds__(256) void conv_kernel(const unsigned int* __restrict__ disp,
                                                   const float* __restrict__ wd,
                                                   float* __restrict__ feat) {
    const int blk = blockIdx.x;            // 2048 = 64bt * 4mh * 8cq
    const int bt = blk >> 5;
    const int inner = blk & 31;
    const int mh = inner >> 3, cq = inner & 7;
    const int tid = threadIdx.x;
    const int lane = tid & 63, w = tid >> 6;
    const int m0 = mh * 16 + w * 4;
    const int c0 = cq * 128 + lane;        // and c0+64
    // one-time weight load + convert (reused across all 12 (m,tap) tiles)
    const float4 wv0 = ((const float4*)wd)[c0];
    const float4 wv1 = ((const float4*)wd)[c0 + 64];
    const __half2 w0x = __float2half2_rn(wv0.x), w0y = __float2half2_rn(wv0.y), w0z = __float2half2_rn(wv0.z);
    const __half2 w1x = __float2half2_rn(wv1.x), w1y = __float2half2_rn(wv1.y), w1z = __float2half2_rn(wv1.z);
    float acc0[4], acc1[4];
    #pragma unroll
    for (int i = 0; i < 4; ++i) { acc0[i] = 0.0f; acc1[i] = 0.0f; }

    #pragma unroll
    for (int mi = 0; mi < 4; ++mi) {
        const int m = m0 + mi;
        #pragma unroll
        for (int tap = 0; tap < 3; ++tap) {
            const uint4* dp = (const uint4*)(disp + ((size_t)((bt * NM + m) * 3 + tap)) * 48);
            unsigned int X[16], Y[16], Z[16];
            #pragma unroll
            for (int qq = 0; qq < 4; ++qq) {
                uint4 u = dp[qq];
                X[4 * qq] = u.x; X[4 * qq + 1] = u.y; X[4 * qq + 2] = u.z; X[4 * qq + 3] = u.w;
                u = dp[4 + qq];
                Y[4 * qq] = u.x; Y[4 * qq + 1] = u.y; Y[4 * qq + 2] = u.z; Y[4 * qq + 3] = u.w;
                u = dp[8 + qq];
                Z[4 * qq] = u.x; Z[4 * qq + 1] = u.y; Z[4 * qq + 2] = u.z; Z[4 * qq + 3] = u.w;
            }
            __half2 a0, a1;
            #pragma unroll
            for (int j = 0; j < 16; ++j) {
                const __half2 hx = *(const __half2*)&X[j];
                const __half2 hy = *(const __half2*)&Y[j];
                const __half2 hz = *(const __half2*)&Z[j];
                const __half2 s0 = __hfma2(w0x, hx, __hfma2(w0y, hy, __hmul2(w0z, hz)));
                const __half2 s1 = __hfma2(w1x, hx, __hfma2(w1y, hy, __hmul2(w1z, hz)));
                a0 = (j == 0) ? s0 : h2max(a0, s0);
                a1 = (j == 0) ? s1 : h2max(a1, s1);
            }
            const float dtf = (float)(tap - 1);
            const float mx0 = fmaxf(__low2float(a0), __high2float(a0));
            const float mx1 = fmaxf(__low2float(a1), __high2float(a1));
            acc0[mi] += fmaxf(0.0f, mx0 + wv0.w * dtf);   // relu/max/+const commute
            acc1[mi] += fmaxf(0.0f, mx1 + wv1.w * dtf);
        }
    }
    float* dst0 = feat + ((size_t)bt * NC + c0) * NM + m0;
    float* dst1 = feat + ((size_t)bt * NC + c0 + 64) * NM + m0;
    *(float4*)dst0 = make_float4(acc0[0], acc0[1], acc0[2], acc0[3]);
    *(float4*)dst1 = make_float4(acc1[0], acc1[1], acc1[2], acc1[3]);
}

extern "C" void kernel_launch(void* const* d_in, const int* in_sizes, int n_in,
                              void* d_out, int out_size, void* d_ws, size_t ws_size,
                              hipStream_t stream) {
    const float* xyzs = (const float*)d_in[0];
    const float* wd   = (const float*)d_in[1];
    float* out_xyz = (float*)d_out;
    float* featp   = out_xyz + NB * NT * NM * 3;         // new_features region
    unsigned int* dispw = (unsigned int*)d_ws;           // 12288*48*4 B = 2.36 MB
    hipLaunchKernelGGL(fps_kernel, dim3(NB * NT), dim3(256), 0, stream, xyzs, out_xyz);
    hipLaunchKernelGGL(bq_kernel, dim3(NB * NT * NM * 3 / 4), dim3(256), 0, stream,
                       xyzs, out_xyz, dispw);
    hipLaunchKernelGGL(conv_kernel, dim3(2048), dim3(256), 0, stream,
                       dispw, wd, featp);
}

// Round 5
// 123.553 us; speedup vs baseline: 1.1591x; 1.1591x over previous
//
#include <hip/hip_runtime.h>
#include <hip/hip_fp16.h>

#define NB 4
#define NT 16
#define NN 2048
#define NM 64
#define NK 32
#define NC 1024

// ROCm 7.2 hip_fp16.h has no __hmax2 — emit v_pk_max_f16 directly.
static __device__ inline __half2 h2max(__half2 a, __half2 b) {
    unsigned int ai = *(unsigned int*)&a, bi = *(unsigned int*)&b, di;
    asm("v_pk_max_f16 %0, %1, %2" : "=v"(di) : "v"(ai), "v"(bi));
    return *(__half2*)&di;
}
static __device__ inline unsigned long long u64max(unsigned long long a, unsigned long long b) {
    return a > b ? a : b;
}

// DPP-based wave64 max reduce step: v = max(v, dpp_move(v)). Invalid lanes
// keep old (=v), which is identity for max. Result of full chain: lane 63
// holds the wave max (row_shr prefix per 16-row, then bcast15/31 merge).
#define DPP_MAX_STEP(v, ctrl)                                                   \
    do {                                                                        \
        const int _mv = __builtin_amdgcn_update_dpp(                            \
            __float_as_int(v), __float_as_int(v), (ctrl), 0xf, 0xf, false);     \
        (v) = fmaxf((v), __int_as_float(_mv));                                  \
    } while (0)

// ---------------------------------------------------------------------------
// Kernel A: FPS, one 256-thr block (4 waves) per frame. Thread tid owns the
// contiguous index run [tid*8, tid*8+8) (lane order == index order), points
// loaded as 6x float4. Wave argmax: DPP value max-reduce -> readlane(63)
// broadcast -> ballot + one shuffle for the exact first-index tie-break
// (logic verified bit-exact in R4). Cross-wave combine: u64 key
// (d2bits<<32 | 2047-idx) in parity LDS, ONE barrier per round.
// Arithmetic (_rn, no FMA) identical to the verified versions.
// ---------------------------------------------------------------------------
__global__ __launch_bounds__(256) void fps_kernel(const float* __restrict__ xyzs,
                                                  float* __restrict__ out_xyz) {
    const int bt = blockIdx.x;
    const float* pts = xyzs + (size_t)bt * NN * 3;
    __shared__ __align__(16) float sP[NN * 3];
    __shared__ unsigned long long sPart[2][4];
    __shared__ float sAnchor[NM * 3];
    const int tid = threadIdx.x;
    const int lane = tid & 63, wave = tid >> 6;
    float wpt[24];
    {
        const float4* pv = (const float4*)pts + (size_t)tid * 6;
        #pragma unroll
        for (int i = 0; i < 6; ++i) {
            const float4 f = pv[i];
            ((float4*)sP)[tid * 6 + i] = f;
            wpt[4 * i + 0] = f.x; wpt[4 * i + 1] = f.y; wpt[4 * i + 2] = f.z; wpt[4 * i + 3] = f.w;
        }
    }
    float px[8], py[8], pz[8], d2[8];
    #pragma unroll
    for (int j = 0; j < 8; ++j) {
        px[j] = wpt[3 * j + 0]; py[j] = wpt[3 * j + 1]; pz[j] = wpt[3 * j + 2];
        d2[j] = 1e10f;
    }
    __syncthreads();
    int last = 0;
    for (int it = 0; it < NM; ++it) {
        const float lx = sP[last * 3 + 0], ly = sP[last * 3 + 1], lz = sP[last * 3 + 2];
        if (tid == 0) {
            sAnchor[it * 3 + 0] = lx; sAnchor[it * 3 + 1] = ly; sAnchor[it * 3 + 2] = lz;
        }
        float bv = -1.0f; int bp = 0;
        #pragma unroll
        for (int j = 0; j < 8; ++j) {
            const float dx = __fsub_rn(px[j], lx), dy = __fsub_rn(py[j], ly), dz = __fsub_rn(pz[j], lz);
            const float d = __fadd_rn(__fadd_rn(__fmul_rn(dx, dx), __fmul_rn(dy, dy)), __fmul_rn(dz, dz));
            d2[j] = fminf(d2[j], d);
            if (d2[j] > bv) { bv = d2[j]; bp = tid * 8 + j; }  // strict > -> first j wins
        }
        // DPP value max-reduce (lane 63 ends with wave max), then broadcast:
        float v = bv;
        DPP_MAX_STEP(v, 0x111);   // row_shr:1
        DPP_MAX_STEP(v, 0x112);   // row_shr:2
        DPP_MAX_STEP(v, 0x114);   // row_shr:4
        DPP_MAX_STEP(v, 0x118);   // row_shr:8
        DPP_MAX_STEP(v, 0x142);   // row_bcast:15
        DPP_MAX_STEP(v, 0x143);   // row_bcast:31
        const float vmax = __int_as_float(__builtin_amdgcn_readlane(__float_as_int(v), 63));
        const unsigned long long tied = __ballot(bv == vmax);
        const int srcLane = (int)(__ffsll((long long)tied) - 1);   // lowest lane = lowest idx
        const int idxw = __shfl(bp, srcLane, 64);
        if (lane == 0)
            sPart[it & 1][wave] = ((unsigned long long)__float_as_uint(vmax) << 32)
                                | (unsigned)(NN - 1 - idxw);
        __syncthreads();
        const unsigned long long key =
            u64max(u64max(sPart[it & 1][0], sPart[it & 1][1]),
                   u64max(sPart[it & 1][2], sPart[it & 1][3]));
        last = NN - 1 - (int)(key & 0xffffffffull);
    }
    __syncthreads();
    for (int i = tid; i < NM * 3; i += 256)
        out_xyz[bt * NM * 3 + i] = sAnchor[i];
}

// ---------------------------------------------------------------------------
// Kernel B: ball query only. One wave per (bt,m,tap) query -> 48 packed half2
// displacement words into d_ws. Semantics identical to the verified R3/R4
// ballot-scan (incl. padding rules).
// ---------------------------------------------------------------------------
__global__ __launch_bounds__(256) void bq_kernel(const float* __restrict__ xyzs,
                                                 const float* __restrict__ anchors,
                                                 unsigned int* __restrict__ disp) {
    const int tid = threadIdx.x;
    const int lane = tid & 63, w = tid >> 6;
    const int q = blockIdx.x * 4 + w;      // (bt*NM + m)*3 + tap
    const int bt = q / (NM * 3);
    const int r = q - bt * (NM * 3);
    const int m = r / 3, tap = r - m * 3;
    const int b = bt >> 4, t = bt & 15;
    __shared__ float sD[4][3][NK];
    const float ax = anchors[(bt * NM + m) * 3 + 0];
    const float ay = anchors[(bt * NM + m) * 3 + 1];
    const float az = anchors[(bt * NM + m) * 3 + 2];
    int tsrc = t + tap - 1;
    tsrc = tsrc < 0 ? 0 : (tsrc > NT - 1 ? NT - 1 : tsrc);
    const float* npts = xyzs + ((size_t)(b * NT + tsrc)) * NN * 3;
    int cnt = 0;
    for (int rr = 0; rr < NN / 64 && cnt < NK; ++rr) {
        const int n = rr * 64 + lane;
        const float dx = __fsub_rn(npts[n * 3 + 0], ax);
        const float dy = __fsub_rn(npts[n * 3 + 1], ay);
        const float dz = __fsub_rn(npts[n * 3 + 2], az);
        const float d2v = __fadd_rn(__fadd_rn(__fmul_rn(dx, dx), __fmul_rn(dy, dy)), __fmul_rn(dz, dz));
        const bool valid = d2v < 0.49f;    // f32(0.7*0.7)
        const unsigned long long mask = __ballot(valid);
        const int pos = cnt + (int)__popcll(mask & ((1ull << lane) - 1ull));
        if (valid && pos < NK) {
            sD[w][0][pos] = dx; sD[w][1][pos] = dy; sD[w][2][pos] = dz;
        }
        cnt += (int)__popcll(mask);
    }
    if (cnt < NK) {   // pad with first valid disp (or neigh[0]-anchor if none)
        float fx, fy, fz;
        if (cnt > 0) {
            fx = sD[w][0][0]; fy = sD[w][1][0]; fz = sD[w][2][0];
        } else {
            fx = __fsub_rn(npts[0], ax); fy = __fsub_rn(npts[1], ay); fz = __fsub_rn(npts[2], az);
        }
        if (lane >= cnt && lane < NK) {
            sD[w][0][lane] = fx; sD[w][1][lane] = fy; sD[w][2][lane] = fz;
        }
    }
    // repack f32 -> half2 pairs along k; layout [x:16][y:16][z:16] u32 words
    if (lane < 48) {
        const int c = lane >> 4, j = lane & 15;
        const __half2 hv = __float22half2_rn(make_float2(sD[w][c][2 * j], sD[w][c][2 * j + 1]));
        disp[(size_t)q * 48 + lane] = *(const unsigned int*)&hv;
    }
}

// ---------------------------------------------------------------------------
// Kernel C: conv + k-maxpool + tap-sum. Pure streaming compute, no LDS.
// 1024 blocks x 256 thr. Block = (bt, 16-m range, 256-channel slice);
// wave = 4 m; lane = 4 channels (c0 + 64*r). 4x compute per tile load vs R4:
// each 48-word disp tile feeds 4 channels -> better latency hiding and half
// the redundant L2 fetches. Weights loaded+converted once per thread.
// ---------------------------------------------------------------------------
__global__ __launch_bounds__(256) void conv_kernel(const unsigned int* __restrict__ disp,
                                                   const float* __restrict__ wd,
                                                   float* __restrict__ feat) {
    const int blk = blockIdx.x;            // 1024 = 64bt * 4mh * 4cq
    const int bt = blk >> 4;
    const int inner = blk & 15;
    const int mh = inner >> 2, cq = inner & 3;
    const int tid = threadIdx.x;
    const int lane = tid & 63, w = tid >> 6;
    const int m0 = mh * 16 + w * 4;
    const int c0 = cq * 256 + lane;        // channels c0 + {0,64,128,192}
    float4 wv[4]; __half2 wx[4], wy[4], wz[4];
    #pragma unroll
    for (int r = 0; r < 4; ++r) {
        wv[r] = ((const float4*)wd)[c0 + 64 * r];
        wx[r] = __float2half2_rn(wv[r].x);
        wy[r] = __float2half2_rn(wv[r].y);
        wz[r] = __float2half2_rn(wv[r].z);
    }
    float acc[4][4];
    #pragma unroll
    for (int r = 0; r < 4; ++r)
        #pragma unroll
        for (int mi = 0; mi < 4; ++mi) acc[r][mi] = 0.0f;

    #pragma unroll
    for (int mi = 0; mi < 4; ++mi) {
        #pragma unroll
        for (int tap = 0; tap < 3; ++tap) {
            const uint4* dp = (const uint4*)(disp + ((size_t)((bt * NM + m0 + mi) * 3 + tap)) * 48);
            uint4 u[12];
            #pragma unroll
            for (int i = 0; i < 12; ++i) u[i] = dp[i];
            const unsigned int* uw = (const unsigned int*)u;   // X[0..15] Y[16..31] Z[32..47]
            __half2 a[4];
            #pragma unroll
            for (int j = 0; j < 16; ++j) {
                const __half2 hx = *(const __half2*)&uw[j];
                const __half2 hy = *(const __half2*)&uw[16 + j];
                const __half2 hz = *(const __half2*)&uw[32 + j];
                #pragma unroll
                for (int r = 0; r < 4; ++r) {
                    const __half2 s = __hfma2(wx[r], hx, __hfma2(wy[r], hy, __hmul2(wz[r], hz)));
                    a[r] = (j == 0) ? s : h2max(a[r], s);
                }
            }
            const float dtf = (float)(tap - 1);
            #pragma unroll
            for (int r = 0; r < 4; ++r) {
                const float mx = fmaxf(__low2float(a[r]), __high2float(a[r]));
                acc[r][mi] += fmaxf(0.0f, mx + wv[r].w * dtf);   // relu/max/+const commute
            }
        }
    }
    #pragma unroll
    for (int r = 0; r < 4; ++r) {
        float* dst = feat + ((size_t)bt * NC + c0 + 64 * r) * NM + m0;
        *(float4*)dst = make_float4(acc[r][0], acc[r][1], acc[r][2], acc[r][3]);
    }
}

extern "C" void kernel_launch(void* const* d_in, const int* in_sizes, int n_in,
                              void* d_out, int out_size, void* d_ws, size_t ws_size,
                              hipStream_t stream) {
    const float* xyzs = (const float*)d_in[0];
    const float* wd   = (const float*)d_in[1];
    float* out_xyz = (float*)d_out;
    float* featp   = out_xyz + NB * NT * NM * 3;         // new_features region
    unsigned int* dispw = (unsigned int*)d_ws;           // 12288*48*4 B = 2.36 MB
    hipLaunchKernelGGL(fps_kernel, dim3(NB * NT), dim3(256), 0, stream, xyzs, out_xyz);
    hipLaunchKernelGGL(bq_kernel, dim3(NB * NT * NM * 3 / 4), dim3(256), 0, stream,
                       xyzs, out_xyz, dispw);
    hipLaunchKernelGGL(conv_kernel, dim3(1024), dim3(256), 0, stream,
                       dispw, wd, featp);
}